// Round 1
// baseline (145.312 us; speedup 1.0000x reference)
//
#include <hip/hip_runtime.h>
#include <stdint.h>

#define B_ 2
#define C_ 512
#define G_ 2048
#define H_ 32
#define D_ 128
#define F_ 64
#define N_ (G_ + C_)      // 2560
#define NPAD 4096
#define CHUNKS 8
#define CHUNK 64          // bottom rows per accum workgroup

// ---------------------------------------------------------------------------
// Kernel 1: per-(b,h) stable descending argsort of 2560 scores via bitonic
// sort of 4096 uint64 keys in LDS. key = (~orderable(score) << 32) | index,
// ascending sort => descending score, ties by ascending index (matches
// stable jnp.argsort(-score)). Writes sorted index array to ws and the
// bit-exact top-G scores to heap_new.
// ---------------------------------------------------------------------------
__global__ __launch_bounds__(512) void sort_kernel(
    const float* __restrict__ heap_score,   // (B,G,H)
    const float* __restrict__ score_c,      // (B,C,H)
    float* __restrict__ heap_new,           // (B,G,H)
    int* __restrict__ ws_idx)               // (B*H, 2560)
{
  __shared__ unsigned long long keys[NPAD];
  const int blk = blockIdx.x;               // b*H + h
  const int b = blk >> 5, h = blk & 31;
  const int tid = threadIdx.x;

  for (int r = tid; r < NPAD; r += 512) {
    unsigned long long key;
    if (r < N_) {
      float s = (r < G_) ? heap_score[((size_t)b * G_ + r) * H_ + h]
                         : score_c[((size_t)b * C_ + (r - G_)) * H_ + h];
      unsigned int bits = __float_as_uint(s);
      unsigned int ord = (bits & 0x80000000u) ? ~bits : (bits | 0x80000000u);
      key = ((unsigned long long)(~ord) << 32) | (unsigned int)r;
    } else {
      key = 0xFFFFFFFFFFFFFFFFull;          // sinks to the end (ascending)
    }
    keys[r] = key;
  }
  __syncthreads();

  for (int k = 2; k <= NPAD; k <<= 1) {
    for (int j = k >> 1; j > 0; j >>= 1) {
      #pragma unroll
      for (int t = tid; t < NPAD / 2; t += 512) {
        int i = ((t & ~(j - 1)) << 1) | (t & (j - 1));
        int p = i | j;
        bool desc = (i & k) != 0;
        unsigned long long a = keys[i], c = keys[p];
        if ((a > c) != desc) { keys[i] = c; keys[p] = a; }
      }
      __syncthreads();
    }
  }

  for (int r = tid; r < N_; r += 512) {
    unsigned long long key = keys[r];
    unsigned int idx = (unsigned int)key;
    ws_idx[blk * N_ + r] = (int)idx;
    if (r < G_) {
      unsigned int ord = ~(unsigned int)(key >> 32);
      unsigned int bits = (ord & 0x80000000u) ? (ord & 0x7FFFFFFFu) : ~ord;
      heap_new[((size_t)b * G_ + r) * H_ + h] = __uint_as_float(bits);
    }
  }
}

// ---------------------------------------------------------------------------
// Kernel 2: row gather. One float4 per thread; rows are (b,g,h), source row
// chosen from *_top (idx < G) or *_c (idx - G). LG = log2(float4 per row).
// ---------------------------------------------------------------------------
template <int LG>
__global__ __launch_bounds__(256) void gather_kernel(
    const float4* __restrict__ src_top,
    const float4* __restrict__ src_c,
    float4* __restrict__ dst,
    const int* __restrict__ ws_idx)
{
  long long gid = (long long)blockIdx.x * 256 + threadIdx.x;
  int row = (int)(gid >> LG);               // [0, B*G*H)
  int lane = (int)(gid & ((1 << LG) - 1));
  int b = row >> 16;                        // G*H = 65536
  int g = (row >> 5) & (G_ - 1);
  int h = row & 31;
  int idx = ws_idx[((b << 5) | h) * N_ + g];
  const float4* src;
  if (idx < G_) src = src_top + (((size_t)(b * G_ + idx) * H_ + h) << LG);
  else          src = src_c  + (((size_t)(b * C_ + (idx - G_)) * H_ + h) << LG);
  dst[gid] = src[lane];
}

// ---------------------------------------------------------------------------
// Kernel 3: per-(b,h) chunk of 64 bottom rows: stage FK (64x64) and V (64x128)
// in LDS, each thread accumulates a 4f x 8d tile over 64 c. Epilogue either
// stores partials to ws (reduced later) or atomic-adds into pre-init output.
// ---------------------------------------------------------------------------
template <bool USE_ATOMIC>
__global__ __launch_bounds__(256) void accum_kernel(
    const float* __restrict__ FK_top, const float* __restrict__ fk_c,
    const float* __restrict__ V_top,  const float* __restrict__ v_c,
    const int* __restrict__ ws_idx,
    float* __restrict__ H_out,        // atomic: H_new (pre-init); else wsH
    float* __restrict__ S_out)        // atomic: S_new (pre-init); else wsS
{
  __shared__ float fk_s[CHUNK][F_];   // 16 KB
  __shared__ float v_s[CHUNK][D_];    // 32 KB
  __shared__ int idx_s[CHUNK];

  const int blk = blockIdx.x;
  const int pair = blk >> 3;          // b*H + h
  const int chunk = blk & 7;
  const int b = pair >> 5, h = pair & 31;
  const int tid = threadIdx.x;

  if (tid < CHUNK) idx_s[tid] = ws_idx[pair * N_ + G_ + chunk * CHUNK + tid];
  __syncthreads();

  for (int i = tid; i < CHUNK * 32; i += 256) {       // V rows, 32 f4/row
    int rr = i >> 5, lane = i & 31;
    int idx = idx_s[rr];
    const float4* src = (idx < G_)
        ? (const float4*)V_top + (((size_t)(b * G_ + idx) * H_ + h) << 5)
        : (const float4*)v_c  + (((size_t)(b * C_ + (idx - G_)) * H_ + h) << 5);
    ((float4*)v_s)[i] = src[lane];
  }
  for (int i = tid; i < CHUNK * 16; i += 256) {       // FK rows, 16 f4/row
    int rr = i >> 4, lane = i & 15;
    int idx = idx_s[rr];
    const float4* src = (idx < G_)
        ? (const float4*)FK_top + (((size_t)(b * G_ + idx) * H_ + h) << 4)
        : (const float4*)fk_c  + (((size_t)(b * C_ + (idx - G_)) * H_ + h) << 4);
    ((float4*)fk_s)[i] = src[lane];
  }
  __syncthreads();

  const int ft = tid >> 4, dt = tid & 15;
  const int f0 = ft * 4, d0 = dt * 8;
  float acc[4][8];
  #pragma unroll
  for (int i = 0; i < 4; i++)
    #pragma unroll
    for (int j = 0; j < 8; j++) acc[i][j] = 0.f;

  for (int cc = 0; cc < CHUNK; ++cc) {
    float4 fk4 = *(const float4*)&fk_s[cc][f0];
    float4 va = *(const float4*)&v_s[cc][d0];
    float4 vb = *(const float4*)&v_s[cc][d0 + 4];
    float fs[4] = {fk4.x, fk4.y, fk4.z, fk4.w};
    float vs[8] = {va.x, va.y, va.z, va.w, vb.x, vb.y, vb.z, vb.w};
    #pragma unroll
    for (int i = 0; i < 4; i++)
      #pragma unroll
      for (int j = 0; j < 8; j++)
        acc[i][j] = fmaf(fs[i], vs[j], acc[i][j]);
  }

  if (USE_ATOMIC) {
    float* Hbase = H_out + ((size_t)pair * F_) * D_;
    #pragma unroll
    for (int i = 0; i < 4; i++)
      #pragma unroll
      for (int j = 0; j < 8; j++)
        atomicAdd(&Hbase[(size_t)(f0 + i) * D_ + d0 + j], acc[i][j]);
    if (tid < F_) {
      float s = 0.f;
      for (int cc = 0; cc < CHUNK; ++cc) s += fk_s[cc][tid];
      atomicAdd(&S_out[(size_t)pair * F_ + tid], s);
    }
  } else {
    float* Hbase = H_out + ((size_t)blk * F_) * D_;   // per-chunk partial
    #pragma unroll
    for (int i = 0; i < 4; i++) {
      float4 lo = {acc[i][0], acc[i][1], acc[i][2], acc[i][3]};
      float4 hi = {acc[i][4], acc[i][5], acc[i][6], acc[i][7]};
      float4* p = (float4*)&Hbase[(size_t)(f0 + i) * D_ + d0];
      p[0] = lo; p[1] = hi;
    }
    if (tid < F_) {
      float s = 0.f;
      for (int cc = 0; cc < CHUNK; ++cc) s += fk_s[cc][tid];
      S_out[(size_t)blk * F_ + tid] = s;
    }
  }
}

// ---------------------------------------------------------------------------
// Kernel 4: reduce 8 chunk partials + H_sum/S_sum into outputs (f4 granular).
// ---------------------------------------------------------------------------
__global__ __launch_bounds__(256) void reduce_kernel(
    const float4* __restrict__ Hsum4, const float4* __restrict__ Ssum4,
    const float4* __restrict__ wsH4,  const float4* __restrict__ wsS4,
    float4* __restrict__ Hnew4,       float4* __restrict__ Snew4)
{
  const int NH4 = B_ * H_ * F_ * D_ / 4;    // 131072
  int gid = blockIdx.x * 256 + threadIdx.x;
  if (gid < NH4) {
    int p = gid >> 11;                      // 2048 f4 per (b,h)
    int e = gid & 2047;
    float4 acc = Hsum4[gid];
    #pragma unroll
    for (int c = 0; c < CHUNKS; ++c) {
      float4 v = wsH4[(((size_t)(p * CHUNKS + c)) << 11) | e];
      acc.x += v.x; acc.y += v.y; acc.z += v.z; acc.w += v.w;
    }
    Hnew4[gid] = acc;
  } else {
    int q = gid - NH4;                      // [0, 1024)
    if (q < B_ * H_ * F_ / 4) {
      int p = q >> 4, fl = q & 15;          // 16 f4 per (b,h)
      float4 acc = Ssum4[q];
      #pragma unroll
      for (int c = 0; c < CHUNKS; ++c) {
        float4 v = wsS4[((p * CHUNKS + c) << 4) | fl];
        acc.x += v.x; acc.y += v.y; acc.z += v.z; acc.w += v.w;
      }
      Snew4[q] = acc;
    }
  }
}

extern "C" void kernel_launch(void* const* d_in, const int* in_sizes, int n_in,
                              void* d_out, int out_size, void* d_ws, size_t ws_size,
                              hipStream_t stream) {
  const float* heap_score = (const float*)d_in[0];
  const float* K_top  = (const float*)d_in[1];
  const float* V_top  = (const float*)d_in[2];
  const float* FK_top = (const float*)d_in[3];
  const float* H_sum  = (const float*)d_in[4];
  const float* S_sum  = (const float*)d_in[5];
  const float* k_c    = (const float*)d_in[6];
  const float* v_c    = (const float*)d_in[7];
  const float* fk_c   = (const float*)d_in[8];
  const float* score_c = (const float*)d_in[9];

  float* out = (float*)d_out;
  float* heap_new = out;                                        // B*G*H
  float* K_new  = heap_new + (size_t)B_ * G_ * H_;              // B*G*H*D
  float* V_new  = K_new + (size_t)B_ * G_ * H_ * D_;
  float* FK_new = V_new + (size_t)B_ * G_ * H_ * D_;            // B*G*H*F
  float* H_new  = FK_new + (size_t)B_ * G_ * H_ * F_;           // B*H*F*D
  float* S_new  = H_new + (size_t)B_ * H_ * F_ * D_;            // B*H*F

  // workspace layout
  int* ws_idx = (int*)d_ws;                                     // 655360 B
  const size_t idx_bytes = (size_t)B_ * H_ * N_ * sizeof(int);
  float* wsH = (float*)((char*)d_ws + idx_bytes);               // 512*8192 f
  float* wsS = wsH + (size_t)B_ * H_ * CHUNKS * F_ * D_;        // 512*64 f
  const size_t ws_needed = idx_bytes
      + (size_t)B_ * H_ * CHUNKS * F_ * D_ * sizeof(float)
      + (size_t)B_ * H_ * CHUNKS * F_ * sizeof(float);

  sort_kernel<<<B_ * H_, 512, 0, stream>>>(heap_score, score_c, heap_new, ws_idx);

  const long long nK = (long long)B_ * G_ * H_ * 32;            // f4 count, D rows
  const long long nF = (long long)B_ * G_ * H_ * 16;            // f4 count, F rows
  gather_kernel<5><<<(int)(nK / 256), 256, 0, stream>>>(
      (const float4*)K_top, (const float4*)k_c, (float4*)K_new, ws_idx);
  gather_kernel<5><<<(int)(nK / 256), 256, 0, stream>>>(
      (const float4*)V_top, (const float4*)v_c, (float4*)V_new, ws_idx);
  gather_kernel<4><<<(int)(nF / 256), 256, 0, stream>>>(
      (const float4*)FK_top, (const float4*)fk_c, (float4*)FK_new, ws_idx);

  if (ws_size >= ws_needed) {
    accum_kernel<false><<<B_ * H_ * CHUNKS, 256, 0, stream>>>(
        FK_top, fk_c, V_top, v_c, ws_idx, wsH, wsS);
    const int ntot4 = B_ * H_ * F_ * D_ / 4 + B_ * H_ * F_ / 4; // 132096
    reduce_kernel<<<(ntot4 + 255) / 256, 256, 0, stream>>>(
        (const float4*)H_sum, (const float4*)S_sum,
        (const float4*)wsH, (const float4*)wsS,
        (float4*)H_new, (float4*)S_new);
  } else {
    hipMemcpyAsync(H_new, H_sum, sizeof(float) * (size_t)B_ * H_ * F_ * D_,
                   hipMemcpyDeviceToDevice, stream);
    hipMemcpyAsync(S_new, S_sum, sizeof(float) * (size_t)B_ * H_ * F_,
                   hipMemcpyDeviceToDevice, stream);
    accum_kernel<true><<<B_ * H_ * CHUNKS, 256, 0, stream>>>(
        FK_top, fk_c, V_top, v_c, ws_idx, H_new, S_new);
  }
}

// Round 2
// 129.065 us; speedup vs baseline: 1.1259x; 1.1259x over previous
//
#include <hip/hip_runtime.h>
#include <stdint.h>

#define B_ 2
#define C_ 512
#define G_ 2048
#define H_ 32
#define D_ 128
#define F_ 64
#define N_ (G_ + C_)      // 2560
#define NPAD 4096
#define CHUNKS 8
#define CHUNK 64          // bottom rows per accum workgroup

// padded LDS slot: one 8B pad per 16 elements -> spreads 64B-contiguous
// per-thread blocks across banks (kills the 32-way conflict).
#define PIDX(i) ((i) + ((i) >> 4))

// ---------------------------------------------------------------------------
// Kernel 1: per-(b,h) stable descending argsort of 2560 scores.
// Bitonic sort of 4096 uint64 keys: 512 threads x 8 register-resident elems.
// key = (~orderable(score) << 32) | index  (keys are UNIQUE -> no ties).
//  - stages k=2..8 + each stage's j<=4 tail: in registers
//  - j==8 step: __shfl_xor with thread t^1 (no LDS at all)
//  - j>=16 steps: LDS compare-exchange on the padded array (conflict-optimal)
// ---------------------------------------------------------------------------
__global__ __launch_bounds__(512) void sort_kernel(
    const float* __restrict__ heap_score,   // (B,G,H)
    const float* __restrict__ score_c,      // (B,C,H)
    float* __restrict__ heap_new,           // (B,G,H)
    int* __restrict__ ws_idx)               // (B*H, 2560)
{
  __shared__ unsigned long long keys[NPAD + (NPAD >> 4)];   // 34 KB
  const int blk = blockIdx.x;               // b*H + h
  const int b = blk >> 5, h = blk & 31;
  const int tid = threadIdx.x;

  for (int r = tid; r < NPAD; r += 512) {
    unsigned long long key;
    if (r < N_) {
      float s = (r < G_) ? heap_score[((size_t)b * G_ + r) * H_ + h]
                         : score_c[((size_t)b * C_ + (r - G_)) * H_ + h];
      unsigned int bits = __float_as_uint(s);
      unsigned int ord = (bits & 0x80000000u) ? ~bits : (bits | 0x80000000u);
      key = ((unsigned long long)(~ord) << 32) | (unsigned int)r;
    } else {
      key = 0xFFFFFFFFFFFFFFFFull;          // sinks to the end (ascending)
    }
    keys[PIDX(r)] = key;
  }
  __syncthreads();

  unsigned long long v[8];
  auto ce = [&](int x, int y, bool desc) {
    unsigned long long a = v[x], c = v[y];
    if ((a > c) != desc) { v[x] = c; v[y] = a; }
  };
  auto shfl64x1 = [](unsigned long long x) {
    unsigned int lo = (unsigned int)x, hi = (unsigned int)(x >> 32);
    lo = __shfl_xor(lo, 1, 64);
    hi = __shfl_xor(hi, 1, 64);
    return ((unsigned long long)hi << 32) | (unsigned long long)lo;
  };
  // j=8 via shuffle with t^1, then j=4,2,1 in registers. desc is uniform
  // across the thread pair (k >= 16 -> direction bit depends on tid>>1 only).
  const bool upper = (tid & 1) != 0;
  auto finish8 = [&](bool desc) {
    #pragma unroll
    for (int l = 0; l < 8; ++l) {
      unsigned long long o = shfl64x1(v[l]);
      unsigned long long mn = (v[l] < o) ? v[l] : o;
      unsigned long long mx = (v[l] < o) ? o : v[l];
      v[l] = (upper != desc) ? mx : mn;
    }
    ce(0,4,desc); ce(1,5,desc); ce(2,6,desc); ce(3,7,desc);
    ce(0,2,desc); ce(1,3,desc); ce(4,6,desc); ce(5,7,desc);
    ce(0,1,desc); ce(2,3,desc); ce(4,5,desc); ce(6,7,desc);
  };

  // ---- own 8 elems; stages k=2,4,8 fully local; stage k=16 via finish8 ----
  #pragma unroll
  for (int l = 0; l < 8; ++l) v[l] = keys[PIDX(tid * 8 + l)];
  {
    const bool t1 = upper;                  // (i & 8) for i = 8*tid + l
    ce(0,1,false); ce(2,3,true);  ce(4,5,false); ce(6,7,true);   // k=2
    ce(0,2,false); ce(1,3,false); ce(4,6,true);  ce(5,7,true);   // k=4 j=2
    ce(0,1,false); ce(2,3,false); ce(4,5,true);  ce(6,7,true);   // k=4 j=1
    ce(0,4,t1); ce(1,5,t1); ce(2,6,t1); ce(3,7,t1);              // k=8 j=4
    ce(0,2,t1); ce(1,3,t1); ce(4,6,t1); ce(5,7,t1);              // k=8 j=2
    ce(0,1,t1); ce(2,3,t1); ce(4,5,t1); ce(6,7,t1);              // k=8 j=1
  }
  finish8((tid & 2) != 0);                  // k=16: desc = (8t & 16)
  #pragma unroll
  for (int l = 0; l < 8; ++l) keys[PIDX(tid * 8 + l)] = v[l];
  __syncthreads();

  // ---- stages k=32..4096 --------------------------------------------------
  for (int k = 32; k <= NPAD; k <<= 1) {
    for (int j = k >> 1; j >= 16; j >>= 1) {
      #pragma unroll
      for (int t = tid; t < NPAD / 2; t += 512) {
        int i = ((t & ~(j - 1)) << 1) | (t & (j - 1));
        int p = i | j;
        bool desc = (i & k) != 0;
        unsigned long long a = keys[PIDX(i)], c = keys[PIDX(p)];
        if ((a > c) != desc) { keys[PIDX(i)] = c; keys[PIDX(p)] = a; }
      }
      __syncthreads();
    }
    const bool desc = ((tid << 3) & k) != 0;
    #pragma unroll
    for (int l = 0; l < 8; ++l) v[l] = keys[PIDX(tid * 8 + l)];
    finish8(desc);
    #pragma unroll
    for (int l = 0; l < 8; ++l) keys[PIDX(tid * 8 + l)] = v[l];
    __syncthreads();
  }

  for (int r = tid; r < N_; r += 512) {
    unsigned long long key = keys[PIDX(r)];
    unsigned int idx = (unsigned int)key;
    ws_idx[blk * N_ + r] = (int)idx;
    if (r < G_) {
      unsigned int ord = ~(unsigned int)(key >> 32);
      unsigned int bits = (ord & 0x80000000u) ? (ord & 0x7FFFFFFFu) : ~ord;
      heap_new[((size_t)b * G_ + r) * H_ + h] = __uint_as_float(bits);
    }
  }
}

// ---------------------------------------------------------------------------
// Kernel 2: fused row gather for K, V, FK with ILP-2 (two independent f4
// copies per thread; both loads issued before either store). gid segments
// (all boundaries multiples of 256 -> wave-uniform branches):
//   [0, nK4) K | [nK4, 2nK4) V | [2nK4, 2nK4+nF4) FK
// ---------------------------------------------------------------------------
__device__ __forceinline__ void gather_decode(
    long long gid,
    const float4* __restrict__ K_top,  const float4* __restrict__ k_c,
    const float4* __restrict__ V_top,  const float4* __restrict__ v_c,
    const float4* __restrict__ FK_top, const float4* __restrict__ fk_c,
    float4* __restrict__ K_new, float4* __restrict__ V_new,
    float4* __restrict__ FK_new,
    const int* __restrict__ ws_idx,
    const float4** src, float4** dst)
{
  const long long nK4 = (long long)B_ * G_ * H_ * (D_ / 4);   // 4194304
  const float4 *top, *cc;
  float4* d;
  int lg;
  long long g2;
  if (gid < nK4)          { top = K_top;  cc = k_c;  d = K_new;  lg = 5; g2 = gid; }
  else if (gid < 2 * nK4) { top = V_top;  cc = v_c;  d = V_new;  lg = 5; g2 = gid - nK4; }
  else                    { top = FK_top; cc = fk_c; d = FK_new; lg = 4; g2 = gid - 2 * nK4; }

  int row = (int)(g2 >> lg);                // [0, B*G*H)
  int lane = (int)(g2 & ((1 << lg) - 1));
  int b = row >> 16;                        // G*H = 65536
  int g = (row >> 5) & (G_ - 1);
  int h = row & 31;
  int idx = ws_idx[((b << 5) | h) * N_ + g];
  if (idx < G_) *src = top + (((size_t)(b * G_ + idx) * H_ + h) << lg) + lane;
  else          *src = cc  + (((size_t)(b * C_ + (idx - G_)) * H_ + h) << lg) + lane;
  *dst = d + g2;
}

__global__ __launch_bounds__(256) void gather_all(
    const float4* __restrict__ K_top,  const float4* __restrict__ k_c,
    const float4* __restrict__ V_top,  const float4* __restrict__ v_c,
    const float4* __restrict__ FK_top, const float4* __restrict__ fk_c,
    float4* __restrict__ K_new, float4* __restrict__ V_new,
    float4* __restrict__ FK_new,
    const int* __restrict__ ws_idx)
{
  const long long half = ((long long)B_ * G_ * H_ * (2 * (D_ / 4) + (F_ / 4))) / 2;
  long long gid = (long long)blockIdx.x * 256 + threadIdx.x;

  const float4 *srcA, *srcB;
  float4 *dstA, *dstB;
  gather_decode(gid, K_top, k_c, V_top, v_c, FK_top, fk_c,
                K_new, V_new, FK_new, ws_idx, &srcA, &dstA);
  gather_decode(gid + half, K_top, k_c, V_top, v_c, FK_top, fk_c,
                K_new, V_new, FK_new, ws_idx, &srcB, &dstB);
  float4 a = *srcA;
  float4 c = *srcB;
  *dstA = a;
  *dstB = c;
}

// ---------------------------------------------------------------------------
// Kernel 3: per-(b,h) chunk of 64 bottom rows: stage FK (64x64) and V (64x128)
// in LDS, each thread accumulates a 4f x 8d tile over 64 c. Epilogue either
// stores partials to ws (reduced later) or atomic-adds into pre-init output.
// ---------------------------------------------------------------------------
template <bool USE_ATOMIC>
__global__ __launch_bounds__(256) void accum_kernel(
    const float* __restrict__ FK_top, const float* __restrict__ fk_c,
    const float* __restrict__ V_top,  const float* __restrict__ v_c,
    const int* __restrict__ ws_idx,
    float* __restrict__ H_out,        // atomic: H_new (pre-init); else wsH
    float* __restrict__ S_out)        // atomic: S_new (pre-init); else wsS
{
  __shared__ float fk_s[CHUNK][F_];   // 16 KB
  __shared__ float v_s[CHUNK][D_];    // 32 KB
  __shared__ int idx_s[CHUNK];

  const int blk = blockIdx.x;
  const int pair = blk >> 3;          // b*H + h
  const int chunk = blk & 7;
  const int b = pair >> 5, h = pair & 31;
  const int tid = threadIdx.x;

  if (tid < CHUNK) idx_s[tid] = ws_idx[pair * N_ + G_ + chunk * CHUNK + tid];
  __syncthreads();

  for (int i = tid; i < CHUNK * 32; i += 256) {       // V rows, 32 f4/row
    int rr = i >> 5, lane = i & 31;
    int idx = idx_s[rr];
    const float4* src = (idx < G_)
        ? (const float4*)V_top + (((size_t)(b * G_ + idx) * H_ + h) << 5)
        : (const float4*)v_c  + (((size_t)(b * C_ + (idx - G_)) * H_ + h) << 5);
    ((float4*)v_s)[i] = src[lane];
  }
  for (int i = tid; i < CHUNK * 16; i += 256) {       // FK rows, 16 f4/row
    int rr = i >> 4, lane = i & 15;
    int idx = idx_s[rr];
    const float4* src = (idx < G_)
        ? (const float4*)FK_top + (((size_t)(b * G_ + idx) * H_ + h) << 4)
        : (const float4*)fk_c  + (((size_t)(b * C_ + (idx - G_)) * H_ + h) << 4);
    ((float4*)fk_s)[i] = src[lane];
  }
  __syncthreads();

  const int ft = tid >> 4, dt = tid & 15;
  const int f0 = ft * 4, d0 = dt * 8;
  float acc[4][8];
  #pragma unroll
  for (int i = 0; i < 4; i++)
    #pragma unroll
    for (int j = 0; j < 8; j++) acc[i][j] = 0.f;

  for (int cc = 0; cc < CHUNK; ++cc) {
    float4 fk4 = *(const float4*)&fk_s[cc][f0];
    float4 va = *(const float4*)&v_s[cc][d0];
    float4 vb = *(const float4*)&v_s[cc][d0 + 4];
    float fs[4] = {fk4.x, fk4.y, fk4.z, fk4.w};
    float vs[8] = {va.x, va.y, va.z, va.w, vb.x, vb.y, vb.z, vb.w};
    #pragma unroll
    for (int i = 0; i < 4; i++)
      #pragma unroll
      for (int j = 0; j < 8; j++)
        acc[i][j] = fmaf(fs[i], vs[j], acc[i][j]);
  }

  if (USE_ATOMIC) {
    float* Hbase = H_out + ((size_t)pair * F_) * D_;
    #pragma unroll
    for (int i = 0; i < 4; i++)
      #pragma unroll
      for (int j = 0; j < 8; j++)
        atomicAdd(&Hbase[(size_t)(f0 + i) * D_ + d0 + j], acc[i][j]);
    if (tid < F_) {
      float s = 0.f;
      for (int cc = 0; cc < CHUNK; ++cc) s += fk_s[cc][tid];
      atomicAdd(&S_out[(size_t)pair * F_ + tid], s);
    }
  } else {
    float* Hbase = H_out + ((size_t)blk * F_) * D_;   // per-chunk partial
    #pragma unroll
    for (int i = 0; i < 4; i++) {
      float4 lo = {acc[i][0], acc[i][1], acc[i][2], acc[i][3]};
      float4 hi = {acc[i][4], acc[i][5], acc[i][6], acc[i][7]};
      float4* p = (float4*)&Hbase[(size_t)(f0 + i) * D_ + d0];
      p[0] = lo; p[1] = hi;
    }
    if (tid < F_) {
      float s = 0.f;
      for (int cc = 0; cc < CHUNK; ++cc) s += fk_s[cc][tid];
      S_out[(size_t)blk * F_ + tid] = s;
    }
  }
}

// ---------------------------------------------------------------------------
// Kernel 4: reduce 8 chunk partials + H_sum/S_sum into outputs (f4 granular).
// ---------------------------------------------------------------------------
__global__ __launch_bounds__(256) void reduce_kernel(
    const float4* __restrict__ Hsum4, const float4* __restrict__ Ssum4,
    const float4* __restrict__ wsH4,  const float4* __restrict__ wsS4,
    float4* __restrict__ Hnew4,       float4* __restrict__ Snew4)
{
  const int NH4 = B_ * H_ * F_ * D_ / 4;    // 131072
  int gid = blockIdx.x * 256 + threadIdx.x;
  if (gid < NH4) {
    int p = gid >> 11;                      // 2048 f4 per (b,h)
    int e = gid & 2047;
    float4 acc = Hsum4[gid];
    #pragma unroll
    for (int c = 0; c < CHUNKS; ++c) {
      float4 v = wsH4[(((size_t)(p * CHUNKS + c)) << 11) | e];
      acc.x += v.x; acc.y += v.y; acc.z += v.z; acc.w += v.w;
    }
    Hnew4[gid] = acc;
  } else {
    int q = gid - NH4;                      // [0, 1024)
    if (q < B_ * H_ * F_ / 4) {
      int p = q >> 4, fl = q & 15;          // 16 f4 per (b,h)
      float4 acc = Ssum4[q];
      #pragma unroll
      for (int c = 0; c < CHUNKS; ++c) {
        float4 v = wsS4[((p * CHUNKS + c) << 4) | fl];
        acc.x += v.x; acc.y += v.y; acc.z += v.z; acc.w += v.w;
      }
      Snew4[q] = acc;
    }
  }
}

extern "C" void kernel_launch(void* const* d_in, const int* in_sizes, int n_in,
                              void* d_out, int out_size, void* d_ws, size_t ws_size,
                              hipStream_t stream) {
  const float* heap_score = (const float*)d_in[0];
  const float* K_top  = (const float*)d_in[1];
  const float* V_top  = (const float*)d_in[2];
  const float* FK_top = (const float*)d_in[3];
  const float* H_sum  = (const float*)d_in[4];
  const float* S_sum  = (const float*)d_in[5];
  const float* k_c    = (const float*)d_in[6];
  const float* v_c    = (const float*)d_in[7];
  const float* fk_c   = (const float*)d_in[8];
  const float* score_c = (const float*)d_in[9];

  float* out = (float*)d_out;
  float* heap_new = out;                                        // B*G*H
  float* K_new  = heap_new + (size_t)B_ * G_ * H_;              // B*G*H*D
  float* V_new  = K_new + (size_t)B_ * G_ * H_ * D_;
  float* FK_new = V_new + (size_t)B_ * G_ * H_ * D_;            // B*G*H*F
  float* H_new  = FK_new + (size_t)B_ * G_ * H_ * F_;           // B*H*F*D
  float* S_new  = H_new + (size_t)B_ * H_ * F_ * D_;            // B*H*F

  // workspace layout
  int* ws_idx = (int*)d_ws;                                     // 655360 B
  const size_t idx_bytes = (size_t)B_ * H_ * N_ * sizeof(int);
  float* wsH = (float*)((char*)d_ws + idx_bytes);               // 512*8192 f
  float* wsS = wsH + (size_t)B_ * H_ * CHUNKS * F_ * D_;        // 512*64 f
  const size_t ws_needed = idx_bytes
      + (size_t)B_ * H_ * CHUNKS * F_ * D_ * sizeof(float)
      + (size_t)B_ * H_ * CHUNKS * F_ * sizeof(float);

  sort_kernel<<<B_ * H_, 512, 0, stream>>>(heap_score, score_c, heap_new, ws_idx);

  const long long ntot = (long long)B_ * G_ * H_ * (2 * (D_ / 4) + (F_ / 4)); // 10485760
  gather_all<<<(int)(ntot / 2 / 256), 256, 0, stream>>>(
      (const float4*)K_top, (const float4*)k_c,
      (const float4*)V_top, (const float4*)v_c,
      (const float4*)FK_top, (const float4*)fk_c,
      (float4*)K_new, (float4*)V_new, (float4*)FK_new, ws_idx);

  if (ws_size >= ws_needed) {
    accum_kernel<false><<<B_ * H_ * CHUNKS, 256, 0, stream>>>(
        FK_top, fk_c, V_top, v_c, ws_idx, wsH, wsS);
    const int ntot4 = B_ * H_ * F_ * D_ / 4 + B_ * H_ * F_ / 4; // 132096
    reduce_kernel<<<(ntot4 + 255) / 256, 256, 0, stream>>>(
        (const float4*)H_sum, (const float4*)S_sum,
        (const float4*)wsH, (const float4*)wsS,
        (float4*)H_new, (float4*)S_new);
  } else {
    hipMemcpyAsync(H_new, H_sum, sizeof(float) * (size_t)B_ * H_ * F_ * D_,
                   hipMemcpyDeviceToDevice, stream);
    hipMemcpyAsync(S_new, S_sum, sizeof(float) * (size_t)B_ * H_ * F_,
                   hipMemcpyDeviceToDevice, stream);
    accum_kernel<true><<<B_ * H_ * CHUNKS, 256, 0, stream>>>(
        FK_top, fk_c, V_top, v_c, ws_idx, H_new, S_new);
  }
}

// Round 3
// 128.410 us; speedup vs baseline: 1.1316x; 1.0051x over previous
//
#include <hip/hip_runtime.h>
#include <stdint.h>

#define B_ 2
#define C_ 512
#define G_ 2048
#define H_ 32
#define D_ 128
#define F_ 64
#define N_ (G_ + C_)      // 2560
#define NPAD 4096
#define CHUNKS 8
#define CHUNK 64          // bottom rows per accum workgroup

// padded LDS slot: one 8B pad per 16 elements -> spreads 64B-contiguous
// per-thread blocks across banks (kills the 32-way conflict).
#define PIDX(i) ((i) + ((i) >> 4))

// ---------------------------------------------------------------------------
// Kernel 1: per-(b,h) stable descending argsort of 2560 scores.
// Bitonic sort of 4096 uint64 keys: 512 threads x 8 register-resident elems.
// key = (~orderable(score) << 32) | index  (keys are UNIQUE -> no ties).
//  - stages k=2..8 + each stage's j<=4 tail: in registers
//  - j==8 step: __shfl_xor with thread t^1 (no LDS at all)
//  - j>=16 steps: LDS compare-exchange on the padded array (conflict-optimal)
// ---------------------------------------------------------------------------
__global__ __launch_bounds__(512) void sort_kernel(
    const float* __restrict__ heap_score,   // (B,G,H)
    const float* __restrict__ score_c,      // (B,C,H)
    float* __restrict__ heap_new,           // (B,G,H)
    int* __restrict__ ws_idx)               // (B*H, 2560)
{
  __shared__ unsigned long long keys[NPAD + (NPAD >> 4)];   // 34 KB
  const int blk = blockIdx.x;               // b*H + h
  const int b = blk >> 5, h = blk & 31;
  const int tid = threadIdx.x;

  for (int r = tid; r < NPAD; r += 512) {
    unsigned long long key;
    if (r < N_) {
      float s = (r < G_) ? heap_score[((size_t)b * G_ + r) * H_ + h]
                         : score_c[((size_t)b * C_ + (r - G_)) * H_ + h];
      unsigned int bits = __float_as_uint(s);
      unsigned int ord = (bits & 0x80000000u) ? ~bits : (bits | 0x80000000u);
      key = ((unsigned long long)(~ord) << 32) | (unsigned int)r;
    } else {
      key = 0xFFFFFFFFFFFFFFFFull;          // sinks to the end (ascending)
    }
    keys[PIDX(r)] = key;
  }
  __syncthreads();

  unsigned long long v[8];
  auto ce = [&](int x, int y, bool desc) {
    unsigned long long a = v[x], c = v[y];
    if ((a > c) != desc) { v[x] = c; v[y] = a; }
  };
  auto shfl64x1 = [](unsigned long long x) {
    unsigned int lo = (unsigned int)x, hi = (unsigned int)(x >> 32);
    lo = __shfl_xor(lo, 1, 64);
    hi = __shfl_xor(hi, 1, 64);
    return ((unsigned long long)hi << 32) | (unsigned long long)lo;
  };
  // j=8 via shuffle with t^1, then j=4,2,1 in registers. desc is uniform
  // across the thread pair (k >= 16 -> direction bit depends on tid>>1 only).
  const bool upper = (tid & 1) != 0;
  auto finish8 = [&](bool desc) {
    #pragma unroll
    for (int l = 0; l < 8; ++l) {
      unsigned long long o = shfl64x1(v[l]);
      unsigned long long mn = (v[l] < o) ? v[l] : o;
      unsigned long long mx = (v[l] < o) ? o : v[l];
      v[l] = (upper != desc) ? mx : mn;
    }
    ce(0,4,desc); ce(1,5,desc); ce(2,6,desc); ce(3,7,desc);
    ce(0,2,desc); ce(1,3,desc); ce(4,6,desc); ce(5,7,desc);
    ce(0,1,desc); ce(2,3,desc); ce(4,5,desc); ce(6,7,desc);
  };

  // ---- own 8 elems; stages k=2,4,8 fully local; stage k=16 via finish8 ----
  #pragma unroll
  for (int l = 0; l < 8; ++l) v[l] = keys[PIDX(tid * 8 + l)];
  {
    const bool t1 = upper;                  // (i & 8) for i = 8*tid + l
    ce(0,1,false); ce(2,3,true);  ce(4,5,false); ce(6,7,true);   // k=2
    ce(0,2,false); ce(1,3,false); ce(4,6,true);  ce(5,7,true);   // k=4 j=2
    ce(0,1,false); ce(2,3,false); ce(4,5,true);  ce(6,7,true);   // k=4 j=1
    ce(0,4,t1); ce(1,5,t1); ce(2,6,t1); ce(3,7,t1);              // k=8 j=4
    ce(0,2,t1); ce(1,3,t1); ce(4,6,t1); ce(5,7,t1);              // k=8 j=2
    ce(0,1,t1); ce(2,3,t1); ce(4,5,t1); ce(6,7,t1);              // k=8 j=1
  }
  finish8((tid & 2) != 0);                  // k=16: desc = (8t & 16)
  #pragma unroll
  for (int l = 0; l < 8; ++l) keys[PIDX(tid * 8 + l)] = v[l];
  __syncthreads();

  // ---- stages k=32..4096 --------------------------------------------------
  for (int k = 32; k <= NPAD; k <<= 1) {
    for (int j = k >> 1; j >= 16; j >>= 1) {
      #pragma unroll
      for (int t = tid; t < NPAD / 2; t += 512) {
        int i = ((t & ~(j - 1)) << 1) | (t & (j - 1));
        int p = i | j;
        bool desc = (i & k) != 0;
        unsigned long long a = keys[PIDX(i)], c = keys[PIDX(p)];
        if ((a > c) != desc) { keys[PIDX(i)] = c; keys[PIDX(p)] = a; }
      }
      __syncthreads();
    }
    const bool desc = ((tid << 3) & k) != 0;
    #pragma unroll
    for (int l = 0; l < 8; ++l) v[l] = keys[PIDX(tid * 8 + l)];
    finish8(desc);
    #pragma unroll
    for (int l = 0; l < 8; ++l) keys[PIDX(tid * 8 + l)] = v[l];
    __syncthreads();
  }

  for (int r = tid; r < N_; r += 512) {
    unsigned long long key = keys[PIDX(r)];
    unsigned int idx = (unsigned int)key;
    ws_idx[blk * N_ + r] = (int)idx;
    if (r < G_) {
      unsigned int ord = ~(unsigned int)(key >> 32);
      unsigned int bits = (ord & 0x80000000u) ? (ord & 0x7FFFFFFFu) : ~ord;
      heap_new[((size_t)b * G_ + r) * H_ + h] = __uint_as_float(bits);
    }
  }
}

// ---------------------------------------------------------------------------
// Kernel 2: fused row gather for K, V, FK with ILP-2 (two independent f4
// copies per thread; both loads issued before either store). gid segments
// (all boundaries multiples of 256 -> wave-uniform branches):
//   [0, nK4) K | [nK4, 2nK4) V | [2nK4, 2nK4+nF4) FK
// ---------------------------------------------------------------------------
__device__ __forceinline__ void gather_decode(
    long long gid,
    const float4* __restrict__ K_top,  const float4* __restrict__ k_c,
    const float4* __restrict__ V_top,  const float4* __restrict__ v_c,
    const float4* __restrict__ FK_top, const float4* __restrict__ fk_c,
    float4* __restrict__ K_new, float4* __restrict__ V_new,
    float4* __restrict__ FK_new,
    const int* __restrict__ ws_idx,
    const float4** src, float4** dst)
{
  const long long nK4 = (long long)B_ * G_ * H_ * (D_ / 4);   // 4194304
  const float4 *top, *cc;
  float4* d;
  int lg;
  long long g2;
  if (gid < nK4)          { top = K_top;  cc = k_c;  d = K_new;  lg = 5; g2 = gid; }
  else if (gid < 2 * nK4) { top = V_top;  cc = v_c;  d = V_new;  lg = 5; g2 = gid - nK4; }
  else                    { top = FK_top; cc = fk_c; d = FK_new; lg = 4; g2 = gid - 2 * nK4; }

  int row = (int)(g2 >> lg);                // [0, B*G*H)
  int lane = (int)(g2 & ((1 << lg) - 1));
  int b = row >> 16;                        // G*H = 65536
  int g = (row >> 5) & (G_ - 1);
  int h = row & 31;
  int idx = ws_idx[((b << 5) | h) * N_ + g];
  if (idx < G_) *src = top + (((size_t)(b * G_ + idx) * H_ + h) << lg) + lane;
  else          *src = cc  + (((size_t)(b * C_ + (idx - G_)) * H_ + h) << lg) + lane;
  *dst = d + g2;
}

__global__ __launch_bounds__(256) void gather_all(
    const float4* __restrict__ K_top,  const float4* __restrict__ k_c,
    const float4* __restrict__ V_top,  const float4* __restrict__ v_c,
    const float4* __restrict__ FK_top, const float4* __restrict__ fk_c,
    float4* __restrict__ K_new, float4* __restrict__ V_new,
    float4* __restrict__ FK_new,
    const int* __restrict__ ws_idx)
{
  const long long half = ((long long)B_ * G_ * H_ * (2 * (D_ / 4) + (F_ / 4))) / 2;
  long long gid = (long long)blockIdx.x * 256 + threadIdx.x;

  const float4 *srcA, *srcB;
  float4 *dstA, *dstB;
  gather_decode(gid, K_top, k_c, V_top, v_c, FK_top, fk_c,
                K_new, V_new, FK_new, ws_idx, &srcA, &dstA);
  gather_decode(gid + half, K_top, k_c, V_top, v_c, FK_top, fk_c,
                K_new, V_new, FK_new, ws_idx, &srcB, &dstB);
  float4 a = *srcA;
  float4 c = *srcB;
  *dstA = a;
  *dstB = c;
}

// ---------------------------------------------------------------------------
// Kernel 3: per-(b,h) chunk of 64 bottom rows: stage FK (64x64) and V (64x128)
// in LDS, each thread accumulates a 4f x 8d tile over 64 c. Epilogue either
// stores partials to ws (reduced later) or atomic-adds into pre-init output.
// ---------------------------------------------------------------------------
template <bool USE_ATOMIC>
__global__ __launch_bounds__(256) void accum_kernel(
    const float* __restrict__ FK_top, const float* __restrict__ fk_c,
    const float* __restrict__ V_top,  const float* __restrict__ v_c,
    const int* __restrict__ ws_idx,
    float* __restrict__ H_out,        // atomic: H_new (pre-init); else wsH
    float* __restrict__ S_out)        // atomic: S_new (pre-init); else wsS
{
  __shared__ float fk_s[CHUNK][F_];   // 16 KB
  __shared__ float v_s[CHUNK][D_];    // 32 KB
  __shared__ int idx_s[CHUNK];

  const int blk = blockIdx.x;
  const int pair = blk >> 3;          // b*H + h
  const int chunk = blk & 7;
  const int b = pair >> 5, h = pair & 31;
  const int tid = threadIdx.x;

  if (tid < CHUNK) idx_s[tid] = ws_idx[pair * N_ + G_ + chunk * CHUNK + tid];
  __syncthreads();

  for (int i = tid; i < CHUNK * 32; i += 256) {       // V rows, 32 f4/row
    int rr = i >> 5, lane = i & 31;
    int idx = idx_s[rr];
    const float4* src = (idx < G_)
        ? (const float4*)V_top + (((size_t)(b * G_ + idx) * H_ + h) << 5)
        : (const float4*)v_c  + (((size_t)(b * C_ + (idx - G_)) * H_ + h) << 5);
    ((float4*)v_s)[i] = src[lane];
  }
  for (int i = tid; i < CHUNK * 16; i += 256) {       // FK rows, 16 f4/row
    int rr = i >> 4, lane = i & 15;
    int idx = idx_s[rr];
    const float4* src = (idx < G_)
        ? (const float4*)FK_top + (((size_t)(b * G_ + idx) * H_ + h) << 4)
        : (const float4*)fk_c  + (((size_t)(b * C_ + (idx - G_)) * H_ + h) << 4);
    ((float4*)fk_s)[i] = src[lane];
  }
  __syncthreads();

  const int ft = tid >> 4, dt = tid & 15;
  const int f0 = ft * 4, d0 = dt * 8;
  float acc[4][8];
  #pragma unroll
  for (int i = 0; i < 4; i++)
    #pragma unroll
    for (int j = 0; j < 8; j++) acc[i][j] = 0.f;

  for (int cc = 0; cc < CHUNK; ++cc) {
    float4 fk4 = *(const float4*)&fk_s[cc][f0];
    float4 va = *(const float4*)&v_s[cc][d0];
    float4 vb = *(const float4*)&v_s[cc][d0 + 4];
    float fs[4] = {fk4.x, fk4.y, fk4.z, fk4.w};
    float vs[8] = {va.x, va.y, va.z, va.w, vb.x, vb.y, vb.z, vb.w};
    #pragma unroll
    for (int i = 0; i < 4; i++)
      #pragma unroll
      for (int j = 0; j < 8; j++)
        acc[i][j] = fmaf(fs[i], vs[j], acc[i][j]);
  }

  if (USE_ATOMIC) {
    float* Hbase = H_out + ((size_t)pair * F_) * D_;
    #pragma unroll
    for (int i = 0; i < 4; i++)
      #pragma unroll
      for (int j = 0; j < 8; j++)
        atomicAdd(&Hbase[(size_t)(f0 + i) * D_ + d0 + j], acc[i][j]);
    if (tid < F_) {
      float s = 0.f;
      for (int cc = 0; cc < CHUNK; ++cc) s += fk_s[cc][tid];
      atomicAdd(&S_out[(size_t)pair * F_ + tid], s);
    }
  } else {
    float* Hbase = H_out + ((size_t)blk * F_) * D_;   // per-chunk partial
    #pragma unroll
    for (int i = 0; i < 4; i++) {
      float4 lo = {acc[i][0], acc[i][1], acc[i][2], acc[i][3]};
      float4 hi = {acc[i][4], acc[i][5], acc[i][6], acc[i][7]};
      float4* p = (float4*)&Hbase[(size_t)(f0 + i) * D_ + d0];
      p[0] = lo; p[1] = hi;
    }
    if (tid < F_) {
      float s = 0.f;
      for (int cc = 0; cc < CHUNK; ++cc) s += fk_s[cc][tid];
      S_out[(size_t)blk * F_ + tid] = s;
    }
  }
}

// ---------------------------------------------------------------------------
// Kernel 4: reduce 8 chunk partials + H_sum/S_sum into outputs (f4 granular).
// ---------------------------------------------------------------------------
__global__ __launch_bounds__(256) void reduce_kernel(
    const float4* __restrict__ Hsum4, const float4* __restrict__ Ssum4,
    const float4* __restrict__ wsH4,  const float4* __restrict__ wsS4,
    float4* __restrict__ Hnew4,       float4* __restrict__ Snew4)
{
  const int NH4 = B_ * H_ * F_ * D_ / 4;    // 131072
  int gid = blockIdx.x * 256 + threadIdx.x;
  if (gid < NH4) {
    int p = gid >> 11;                      // 2048 f4 per (b,h)
    int e = gid & 2047;
    float4 acc = Hsum4[gid];
    #pragma unroll
    for (int c = 0; c < CHUNKS; ++c) {
      float4 v = wsH4[(((size_t)(p * CHUNKS + c)) << 11) | e];
      acc.x += v.x; acc.y += v.y; acc.z += v.z; acc.w += v.w;
    }
    Hnew4[gid] = acc;
  } else {
    int q = gid - NH4;                      // [0, 1024)
    if (q < B_ * H_ * F_ / 4) {
      int p = q >> 4, fl = q & 15;          // 16 f4 per (b,h)
      float4 acc = Ssum4[q];
      #pragma unroll
      for (int c = 0; c < CHUNKS; ++c) {
        float4 v = wsS4[((p * CHUNKS + c) << 4) | fl];
        acc.x += v.x; acc.y += v.y; acc.z += v.z; acc.w += v.w;
      }
      Snew4[q] = acc;
    }
  }
}

extern "C" void kernel_launch(void* const* d_in, const int* in_sizes, int n_in,
                              void* d_out, int out_size, void* d_ws, size_t ws_size,
                              hipStream_t stream) {
  const float* heap_score = (const float*)d_in[0];
  const float* K_top  = (const float*)d_in[1];
  const float* V_top  = (const float*)d_in[2];
  const float* FK_top = (const float*)d_in[3];
  const float* H_sum  = (const float*)d_in[4];
  const float* S_sum  = (const float*)d_in[5];
  const float* k_c    = (const float*)d_in[6];
  const float* v_c    = (const float*)d_in[7];
  const float* fk_c   = (const float*)d_in[8];
  const float* score_c = (const float*)d_in[9];

  float* out = (float*)d_out;
  float* heap_new = out;                                        // B*G*H
  float* K_new  = heap_new + (size_t)B_ * G_ * H_;              // B*G*H*D
  float* V_new  = K_new + (size_t)B_ * G_ * H_ * D_;
  float* FK_new = V_new + (size_t)B_ * G_ * H_ * D_;            // B*G*H*F
  float* H_new  = FK_new + (size_t)B_ * G_ * H_ * F_;           // B*H*F*D
  float* S_new  = H_new + (size_t)B_ * H_ * F_ * D_;            // B*H*F

  // workspace layout
  int* ws_idx = (int*)d_ws;                                     // 655360 B
  const size_t idx_bytes = (size_t)B_ * H_ * N_ * sizeof(int);
  float* wsH = (float*)((char*)d_ws + idx_bytes);               // 512*8192 f
  float* wsS = wsH + (size_t)B_ * H_ * CHUNKS * F_ * D_;        // 512*64 f
  const size_t ws_needed = idx_bytes
      + (size_t)B_ * H_ * CHUNKS * F_ * D_ * sizeof(float)
      + (size_t)B_ * H_ * CHUNKS * F_ * sizeof(float);

  sort_kernel<<<B_ * H_, 512, 0, stream>>>(heap_score, score_c, heap_new, ws_idx);

  const long long ntot = (long long)B_ * G_ * H_ * (2 * (D_ / 4) + (F_ / 4)); // 10485760
  gather_all<<<(int)(ntot / 2 / 256), 256, 0, stream>>>(
      (const float4*)K_top, (const float4*)k_c,
      (const float4*)V_top, (const float4*)v_c,
      (const float4*)FK_top, (const float4*)fk_c,
      (float4*)K_new, (float4*)V_new, (float4*)FK_new, ws_idx);

  if (ws_size >= ws_needed) {
    accum_kernel<false><<<B_ * H_ * CHUNKS, 256, 0, stream>>>(
        FK_top, fk_c, V_top, v_c, ws_idx, wsH, wsS);
    const int ntot4 = B_ * H_ * F_ * D_ / 4 + B_ * H_ * F_ / 4; // 132096
    reduce_kernel<<<(ntot4 + 255) / 256, 256, 0, stream>>>(
        (const float4*)H_sum, (const float4*)S_sum,
        (const float4*)wsH, (const float4*)wsS,
        (float4*)H_new, (float4*)S_new);
  } else {
    hipMemcpyAsync(H_new, H_sum, sizeof(float) * (size_t)B_ * H_ * F_ * D_,
                   hipMemcpyDeviceToDevice, stream);
    hipMemcpyAsync(S_new, S_sum, sizeof(float) * (size_t)B_ * H_ * F_,
                   hipMemcpyDeviceToDevice, stream);
    accum_kernel<true><<<B_ * H_ * CHUNKS, 256, 0, stream>>>(
        FK_top, fk_c, V_top, v_c, ws_idx, H_new, S_new);
  }
}